// Round 6
// baseline (166.204 us; speedup 1.0000x reference)
//
#include <hip/hip_runtime.h>
#include <math.h>

typedef unsigned int uint32;
typedef unsigned short u16;

typedef __bf16 bf16x8 __attribute__((ext_vector_type(8)));
typedef float f32x4 __attribute__((ext_vector_type(4)));

constexpr int NB = 8, NC = 256, NN = 4096;
constexpr int GS = 160;  // LDS g-slab row width (floats); 160%32==0 but reads are c-uniform (conflict-free), writes 4-way (cheap)

// Static device scratch; fully rewritten every launch.
__device__ __attribute__((aligned(16))) u16 g_x2h[NB * NN * NC];  // 16 MB
__device__ __attribute__((aligned(16))) u16 g_x2l[NB * NN * NC];  // 16 MB
__device__ __attribute__((aligned(16))) u16 g_wgh[NC * NC];
__device__ __attribute__((aligned(16))) u16 g_wgl[NC * NC];

__device__ __forceinline__ u16 bf16_rne(float f) {
    uint32 u = __float_as_uint(f);
    u += 0x7FFFu + ((u >> 16) & 1u);
    return (u16)(u >> 16);
}

__device__ __forceinline__ float dinv_of(int n) {
    int lo = n - 9; lo = lo < 0 ? 0 : lo;
    int hi = n + 9; hi = hi > NN - 1 ? NN - 1 : hi;
    return 1.0f / sqrtf((float)(hi - lo + 1));  // deg incl. self-loop
}

// ---------------------------------------------------------------------------
// K0: (a) permute x -> x2[b][n][k] with n = ch + 256*t, x2[n][k] = x[b][ch][16k+t],
//     split fp32 into bf16 hi/lo.  (b) transpose+split Wg -> Wgt[c][k] hi/lo.
// ---------------------------------------------------------------------------
__global__ __launch_bounds__(256) void kprep(const float* __restrict__ x,
                                             const float* __restrict__ wg) {
    __shared__ float sm[4096];
    const int bid = blockIdx.x, tid = threadIdx.x;
    if (bid < NB * NC) {
        const int b = bid >> 8, ch = bid & 255;
        const float4* src = reinterpret_cast<const float4*>(x) + ((size_t)(b * NC + ch) << 10);
        float4* s4 = reinterpret_cast<float4*>(sm);
#pragma unroll
        for (int v = 0; v < 4; ++v) s4[v * 256 + tid] = src[v * 256 + tid];
        __syncthreads();
        const int t = tid & 15, kb = tid >> 4;
        uint32 hp[8], lp[8];
#pragma unroll
        for (int w = 0; w < 8; ++w) {
            float f0 = sm[256 * kb + 16 * (2 * w) + t];
            float f1 = sm[256 * kb + 16 * (2 * w + 1) + t];
            u16 h0 = bf16_rne(f0), h1 = bf16_rne(f1);
            float r0 = f0 - __uint_as_float((uint32)h0 << 16);
            float r1 = f1 - __uint_as_float((uint32)h1 << 16);
            hp[w] = (uint32)h0 | ((uint32)h1 << 16);
            lp[w] = (uint32)bf16_rne(r0) | ((uint32)bf16_rne(r1) << 16);
        }
        const int n = ch + (t << 8);
        const size_t off = (((size_t)b << 12) + n) * NC + kb * 16;
        uint4* dh = reinterpret_cast<uint4*>(g_x2h + off);
        uint4* dl = reinterpret_cast<uint4*>(g_x2l + off);
        dh[0] = make_uint4(hp[0], hp[1], hp[2], hp[3]);
        dh[1] = make_uint4(hp[4], hp[5], hp[6], hp[7]);
        dl[0] = make_uint4(lp[0], lp[1], lp[2], lp[3]);
        dl[1] = make_uint4(lp[4], lp[5], lp[6], lp[7]);
    } else {
        const int b2 = bid - NB * NC;
        const int k0 = (b2 >> 3) * 32, c0 = (b2 & 7) * 32;
        {
            const int r = tid >> 3, cq = tid & 7;
            float4 v = *reinterpret_cast<const float4*>(wg + (k0 + r) * NC + c0 + cq * 4);
            float* d = sm + r * 33 + cq * 4;
            d[0] = v.x; d[1] = v.y; d[2] = v.z; d[3] = v.w;
        }
        __syncthreads();
        const int c = tid >> 3, kq = tid & 7;
        uint32 hp[2], lp[2];
#pragma unroll
        for (int w = 0; w < 2; ++w) {
            float f0 = sm[(kq * 4 + 2 * w) * 33 + c];
            float f1 = sm[(kq * 4 + 2 * w + 1) * 33 + c];
            u16 h0 = bf16_rne(f0), h1 = bf16_rne(f1);
            float r0 = f0 - __uint_as_float((uint32)h0 << 16);
            float r1 = f1 - __uint_as_float((uint32)h1 << 16);
            hp[w] = (uint32)h0 | ((uint32)h1 << 16);
            lp[w] = (uint32)bf16_rne(r0) | ((uint32)bf16_rne(r1) << 16);
        }
        const int off = (c0 + c) * NC + k0 + kq * 4;
        *reinterpret_cast<uint2*>(g_wgh + off) = make_uint2(hp[0], hp[1]);
        *reinterpret_cast<uint2*>(g_wgl + off) = make_uint2(lp[0], lp[1]);
    }
}

__device__ __forceinline__ bf16x8 ldb8(const u16* p) {
    return __builtin_bit_cast(bf16x8, *reinterpret_cast<const uint4*>(p));
}

// ---------------------------------------------------------------------------
// Fused hT-GEMM + band + bias, writing out[b][c][n] directly.
//   hT[c][n] = sum_k Wgt[c][k] * x2[n][k]   (A = Wgt rows -> D rows = c;
//                                            B = x2 rows  -> D cols = n)
//   g[c][n]  = dinv[n] * hT[c][n]  (0 for OOB halo n)
//   out[b][c][n] = dinv[n] * sum_{q=-9..9} g[c][n+q] + bias[c]
// Grid: 8 b x 2 c-tiles(128) x 32 n-tiles(128) = 512 blocks, 4 waves.
// Wave: 32 c-rows x 160 n-extent (16 halo each side). Band via per-wave
// 16x160 LDS slab, two c-frag passes (40 KB/block total).
// ---------------------------------------------------------------------------
__global__ __launch_bounds__(256, 2) void kfuse(const float* __restrict__ bias,
                                                float* __restrict__ out) {
    __shared__ float gt[4][16 * GS];
    const int bid = blockIdx.x, tid = threadIdx.x;
    const int b = bid >> 6;
    const int ct = (bid >> 5) & 1, nt = bid & 31;
    const int w = tid >> 6, l = tid & 63;
    const int lr = l & 15, lk = l >> 4;
    const int cg0 = ct * 128 + w * 32;   // wave c-base
    const int n0 = nt * 128;             // output n-base
    const int ne0 = n0 - 16;             // halo extent base

    // row offsets (elements) into the split buffers
    const int aoff0 = (cg0 + lr) * NC + lk * 8;
    const int aoff1 = aoff0 + 16 * NC;
    int boff[10];
#pragma unroll
    for (int j = 0; j < 10; ++j) {
        int r = ne0 + j * 16 + lr;
        r = r < 0 ? 0 : (r > NN - 1 ? NN - 1 : r);   // clamp; masked later
        boff[j] = (b * NN + r) * NC + lk * 8;
    }

    f32x4 acc[2][10] = {};
    for (int kb = 0; kb < NC; kb += 32) {
        bf16x8 a0h = ldb8(g_wgh + aoff0 + kb), a0l = ldb8(g_wgl + aoff0 + kb);
        bf16x8 a1h = ldb8(g_wgh + aoff1 + kb), a1l = ldb8(g_wgl + aoff1 + kb);
        bf16x8 bh[10], bl[10];
#pragma unroll
        for (int j = 0; j < 10; ++j) {
            bh[j] = ldb8(g_x2h + boff[j] + kb);
            bl[j] = ldb8(g_x2l + boff[j] + kb);
        }
#pragma unroll
        for (int j = 0; j < 10; ++j) {
            acc[0][j] = __builtin_amdgcn_mfma_f32_16x16x32_bf16(a0h, bh[j], acc[0][j], 0, 0, 0);
            acc[0][j] = __builtin_amdgcn_mfma_f32_16x16x32_bf16(a0h, bl[j], acc[0][j], 0, 0, 0);
            acc[0][j] = __builtin_amdgcn_mfma_f32_16x16x32_bf16(a0l, bh[j], acc[0][j], 0, 0, 0);
            acc[1][j] = __builtin_amdgcn_mfma_f32_16x16x32_bf16(a1h, bh[j], acc[1][j], 0, 0, 0);
            acc[1][j] = __builtin_amdgcn_mfma_f32_16x16x32_bf16(a1h, bl[j], acc[1][j], 0, 0, 0);
            acc[1][j] = __builtin_amdgcn_mfma_f32_16x16x32_bf16(a1l, bh[j], acc[1][j], 0, 0, 0);
        }
    }

    // per-lane dinv for its col within each n-frag (0 for OOB halo)
    float dv[10];
#pragma unroll
    for (int j = 0; j < 10; ++j) {
        int n = ne0 + j * 16 + lr;
        dv[j] = (n >= 0 && n < NN) ? dinv_of(n) : 0.f;
    }
    const float dva = dinv_of(n0 + l), dvb = dinv_of(n0 + 64 + l);

    float* g = gt[w];
    for (int ci = 0; ci < 2; ++ci) {
        if (ci) __syncthreads();  // pass-0 reads done before pass-1 overwrites
#pragma unroll
        for (int j = 0; j < 10; ++j)
#pragma unroll
            for (int v = 0; v < 4; ++v)
                g[(lk * 4 + v) * GS + j * 16 + lr] = acc[ci][j][v] * dv[j];
        __syncthreads();

        float* orow = out + (((size_t)(b * NC + cg0 + ci * 16)) << 12) + n0;
        const float* bp = bias + cg0 + ci * 16;
        for (int c = 0; c < 16; ++c) {
            const float bc = bp[c];
            const float* gr = g + c * GS;
            float s0 = 0.f, s1 = 0.f;
#pragma unroll
            for (int q = 0; q < 19; ++q) {
                s0 += gr[l + 7 + q];    // window for n = n0 + l
                s1 += gr[l + 71 + q];   // window for n = n0 + 64 + l
            }
            orow[l]      = s0 * dva + bc;
            orow[64 + l] = s1 * dvb + bc;
            orow += NN;
        }
    }
}

extern "C" void kernel_launch(void* const* d_in, const int* in_sizes, int n_in,
                              void* d_out, int out_size, void* d_ws, size_t ws_size,
                              hipStream_t stream) {
    const float* x  = (const float*)d_in[0];
    const float* wg = (const float*)d_in[1];
    const float* bs = (const float*)d_in[2];
    float* out = (float*)d_out;

    hipLaunchKernelGGL(kprep, dim3(NB * NC + 64), dim3(256), 0, stream, x, wg);
    hipLaunchKernelGGL(kfuse, dim3(512), dim3(256), 0, stream, bs, out);
}

// Round 9
// 112.409 us; speedup vs baseline: 1.4786x; 1.4786x over previous
//
#include <hip/hip_runtime.h>
#include <math.h>

typedef unsigned int uint32;
typedef unsigned short u16;
typedef _Float16 half8 __attribute__((ext_vector_type(8)));
typedef float f32x4 __attribute__((ext_vector_type(4)));

constexpr int NB = 8, NC = 256, NN = 4096;

// fp16 permuted x2[b][n][k], 16B-chunks XOR-swizzled within each 64B sub-row
// (key = (n>>1)&3). Fully rewritten every launch.
__device__ __attribute__((aligned(16))) u16 g_xf[NB * NN * NC];  // 16.8 MB
__device__ __attribute__((aligned(16))) u16 g_wf[NC * NC];       // Wg^T [c][k] fp16

__device__ __forceinline__ float dinv_of(int n) {
    int lo = n - 9; lo = lo < 0 ? 0 : lo;
    int hi = n + 9; hi = hi > NN - 1 ? NN - 1 : hi;
    return 1.0f / sqrtf((float)(hi - lo + 1));  // deg incl. self-loop
}

__device__ __forceinline__ uint32 pkh(float a, float b) {
    _Float16 ha = (_Float16)a, hb = (_Float16)b;
    return (uint32)__builtin_bit_cast(u16, ha) | ((uint32)__builtin_bit_cast(u16, hb) << 16);
}

__device__ __forceinline__ half8 ldh8(const u16* p) {
    return __builtin_bit_cast(half8, *reinterpret_cast<const uint4*>(p));
}

// ---------------------------------------------------------------------------
// kprep: x2[b][n=ch+256t][k] = x[b][ch][16k+t] -> fp16, chunk-swizzled.
// Plane path: no LDS/barrier; strided dword loads (sector-efficient via L1
// reuse across the block's waves), 2 coalesced 16B chunk stores per thread
// (16 threads of same t -> 256B contiguous). Wg path: 32x32 LDS transpose.
// ---------------------------------------------------------------------------
__global__ __launch_bounds__(256) void kprep(const float* __restrict__ x,
                                             const float* __restrict__ wg) {
    const int bid = blockIdx.x, tid = threadIdx.x;
    if (bid < NB * NC) {
        const int b = bid >> 8, ch = bid & 255;
        const float* P = x + ((size_t)(b * NC + ch) << 12);
        const int t = tid >> 4, kb2 = tid & 15;
        const int n = ch + (t << 8);
        const int key = (ch >> 1) & 3;  // == (n>>1)&3 since 256t>>1 === 0 mod 4
        u16* row = g_xf + (((size_t)b << 12) + n) * NC;
#pragma unroll
        for (int h = 0; h < 2; ++h) {
            const int chunk = kb2 + h * 16;  // 8 k-values per 16B chunk
            uint32 pk[4];
#pragma unroll
            for (int p = 0; p < 4; ++p) {
                float f0 = P[(chunk * 8 + 2 * p) * 16 + t];
                float f1 = P[(chunk * 8 + 2 * p + 1) * 16 + t];
                pk[p] = pkh(f0, f1);
            }
            const int phys = (chunk & ~3) | ((chunk & 3) ^ key);
            *reinterpret_cast<uint4*>(row + phys * 8) = make_uint4(pk[0], pk[1], pk[2], pk[3]);
        }
    } else {
        __shared__ float sm[32 * 33];
        const int b2 = bid - NB * NC;
        const int k0 = (b2 >> 3) * 32, c0 = (b2 & 7) * 32;
        {
            const int r = tid >> 3, cq = tid & 7;
            float4 v = *reinterpret_cast<const float4*>(wg + (k0 + r) * NC + c0 + cq * 4);
            float* d = sm + r * 33 + cq * 4;
            d[0] = v.x; d[1] = v.y; d[2] = v.z; d[3] = v.w;
        }
        __syncthreads();
        const int c = tid >> 3, kq = tid & 7;
        uint32 o0 = pkh(sm[(kq * 4 + 0) * 33 + c], sm[(kq * 4 + 1) * 33 + c]);
        uint32 o1 = pkh(sm[(kq * 4 + 2) * 33 + c], sm[(kq * 4 + 3) * 33 + c]);
        *reinterpret_cast<uint2*>(g_wf + (c0 + c) * NC + k0 + kq * 4) = make_uint2(o0, o1);
    }
}

// ---------------------------------------------------------------------------
// kfuse: hT-GEMM (fp16) + band-GEMM + bias, writes out[b][c][n] directly.
// Grid 512 = 8b x 2ct(128c) x 32nt(128n); 4 waves; wave = 32c x 160n-ext.
// B-tile (160 x 32k) double-buffered via global_load_lds(16B), shared by all
// waves; A (Wgt) preloaded to regs. Band: out[c,n] = sum_j g[c,j]*Bnd[j,n]
// via MFMA with in-register 0/1 Bnd; only KB in {f>>1, f>>1+1} contribute.
// ---------------------------------------------------------------------------
__global__ __launch_bounds__(256, 2) void kfuse(const float* __restrict__ bias,
                                                float* __restrict__ out) {
    __shared__ __attribute__((aligned(16))) char smem[43008];  // [2][10240] B-dbuf; then 4 x 10752 g-slab
    const int bid = blockIdx.x, tid = threadIdx.x;
    const int b = bid >> 6, ct = (bid >> 5) & 1, nt = bid & 31;
    const int w = tid >> 6, l = tid & 63;
    const int lr = l & 15, lk = l >> 4;
    const int wc0 = ct * 128 + w * 32;
    const int n0 = nt * 128, ne0 = n0 - 16;
    const int koff = (lk ^ ((lr >> 1) & 3)) << 4;  // de-swizzle byte offset

    // staging: 10 sub-tiles (16 rows x 64B) over 4 waves (w<2: 3, else 2)
    const int ni = (w < 2) ? 3 : 2;
    const char* gxc = (const char*)g_xf;
    size_t sgb[3]; int sld[3];
#pragma unroll
    for (int ii = 0; ii < 3; ++ii) {
        const int i = w + ii * 4;
        int n = ne0 + i * 16 + (l >> 2);
        n = n < 0 ? 0 : (n > NN - 1 ? NN - 1 : n);  // clamp; masked at g-slab
        sgb[ii] = (size_t)((b << 12) + n) * 512 + (l & 3) * 16;
        sld[ii] = i * 1024 + l * 16;
    }

    // preload all A fragments (Wgt fp16, L2-resident): 16 x 16B
    half8 af[8][2];
#pragma unroll
    for (int s = 0; s < 8; ++s)
#pragma unroll
        for (int cf = 0; cf < 2; ++cf)
            af[s][cf] = ldh8(g_wf + (wc0 + cf * 16 + lr) * NC + s * 32 + lk * 8);

    f32x4 acc[2][10] = {};

#define STAGE(CUR, S)                                                                         \
    _Pragma("unroll")                                                                         \
    for (int ii = 0; ii < 3; ++ii)                                                            \
        if (ii < ni)                                                                          \
            __builtin_amdgcn_global_load_lds(                                                 \
                (const __attribute__((address_space(1))) uint32*)(gxc + sgb[ii] + (S) * 64),  \
                (__attribute__((address_space(3))) uint32*)(smem + (CUR) * 10240 + sld[ii]),  \
                16, 0, 0);

    STAGE(0, 0)
    __syncthreads();
#pragma unroll
    for (int s = 0; s < 8; ++s) {
        const int cur = s & 1;
        if (s < 7) { STAGE(cur ^ 1, s + 1) }
        const char* bb = smem + cur * 10240;
#pragma unroll
        for (int f = 0; f < 10; ++f) {
            half8 bf = *reinterpret_cast<const half8*>(bb + (f * 16 + lr) * 64 + koff);
            acc[0][f] = __builtin_amdgcn_mfma_f32_16x16x32_f16(af[s][0], bf, acc[0][f], 0, 0, 0);
            acc[1][f] = __builtin_amdgcn_mfma_f32_16x16x32_f16(af[s][1], bf, acc[1][f], 0, 0, 0);
        }
        __syncthreads();  // next stage landed; everyone done reading cur
    }
#undef STAGE

    // g-slab: fp16 g = dinv_j * h (0 for OOB halo). 32 c-rows x 160 j, pitch 336B.
    char* gsl = smem + w * 10752;
    float dv[10];
#pragma unroll
    for (int f = 0; f < 10; ++f) {
        int n = ne0 + f * 16 + lr;
        dv[f] = (n >= 0 && n < NN) ? dinv_of(n) : 0.f;
    }
#pragma unroll
    for (int cf = 0; cf < 2; ++cf)
#pragma unroll
        for (int f = 0; f < 10; ++f)
#pragma unroll
            for (int v = 0; v < 4; ++v) {
                const int crow = cf * 16 + 4 * lk + v;
                _Float16 hv = (_Float16)(acc[cf][f][v] * dv[f]);
                *(u16*)(gsl + crow * 336 + (f * 16 + lr) * 2) = __builtin_bit_cast(u16, hv);
            }
    __syncthreads();  // also fences B-dbuf -> g-slab LDS reuse

    // band GEMM: out block f needs only KB = f>>1 and f>>1 + 1
    f32x4 acc2[2][8] = {};
#pragma unroll
    for (int f = 0; f < 8; ++f)
#pragma unroll
        for (int t = 0; t < 2; ++t) {
            const int KB = (f >> 1) + t;
            half8 ga0 = *reinterpret_cast<const half8*>(gsl + lr * 336 + KB * 64 + lk * 16);
            half8 ga1 = *reinterpret_cast<const half8*>(gsl + (16 + lr) * 336 + KB * 64 + lk * 16);
            const int base = KB * 32 + lk * 8 - 16 - f * 16 - lr;  // d = j - n_local - 16
            half8 bn;
#pragma unroll
            for (int jj = 0; jj < 8; ++jj) {
                const int d = base + jj;
                bn[jj] = (d >= -9 && d <= 9) ? (_Float16)1.f : (_Float16)0.f;
            }
            acc2[0][f] = __builtin_amdgcn_mfma_f32_16x16x32_f16(ga0, bn, acc2[0][f], 0, 0, 0);
            acc2[1][f] = __builtin_amdgcn_mfma_f32_16x16x32_f16(ga1, bn, acc2[1][f], 0, 0, 0);
        }

    float dnv[8];
#pragma unroll
    for (int f = 0; f < 8; ++f) dnv[f] = dinv_of(n0 + f * 16 + lr);
#pragma unroll
    for (int cf = 0; cf < 2; ++cf)
#pragma unroll
        for (int v = 0; v < 4; ++v) {
            const int c = wc0 + cf * 16 + 4 * lk + v;
            const float bc = bias[c];
            float* orow = out + (((size_t)(b * NC + c)) << 12) + n0;
#pragma unroll
            for (int f = 0; f < 8; ++f)
                orow[f * 16 + lr] = acc2[cf][f][v] * dnv[f] + bc;
        }
}

extern "C" void kernel_launch(void* const* d_in, const int* in_sizes, int n_in,
                              void* d_out, int out_size, void* d_ws, size_t ws_size,
                              hipStream_t stream) {
    const float* x  = (const float*)d_in[0];
    const float* wg = (const float*)d_in[1];
    const float* bs = (const float*)d_in[2];
    float* out = (float*)d_out;

    hipLaunchKernelGGL(kprep, dim3(NB * NC + 64), dim3(256), 0, stream, x, wg);
    hipLaunchKernelGGL(kfuse, dim3(512), dim3(256), 0, stream, bs, out);
}

// Round 10
// 102.659 us; speedup vs baseline: 1.6190x; 1.0950x over previous
//
#include <hip/hip_runtime.h>
#include <math.h>

typedef unsigned int uint32;
typedef unsigned short u16;
typedef _Float16 half8 __attribute__((ext_vector_type(8)));
typedef float f32x4 __attribute__((ext_vector_type(4)));

constexpr int NB = 8, NC = 256, NN = 4096;

// fp16 permuted x2[b][n][k], 16B-chunks XOR-swizzled within each 64B sub-row
// (key = (n>>1)&3). Fully rewritten every launch.
__device__ __attribute__((aligned(16))) u16 g_xf[NB * NN * NC];  // 16.8 MB
__device__ __attribute__((aligned(16))) u16 g_wf[NC * NC];       // Wg^T [c][k] fp16

__device__ __forceinline__ float dinv_of(int n) {
    int lo = n - 9; lo = lo < 0 ? 0 : lo;
    int hi = n + 9; hi = hi > NN - 1 ? NN - 1 : hi;
    return 1.0f / sqrtf((float)(hi - lo + 1));  // deg incl. self-loop
}

__device__ __forceinline__ uint32 pkh(float a, float b) {
    _Float16 ha = (_Float16)a, hb = (_Float16)b;
    return (uint32)__builtin_bit_cast(u16, ha) | ((uint32)__builtin_bit_cast(u16, hb) << 16);
}

__device__ __forceinline__ half8 ldh8(const u16* p) {
    return __builtin_bit_cast(half8, *reinterpret_cast<const uint4*>(p));
}

// ---------------------------------------------------------------------------
// kprep: x2[b][n=ch+256t][k] = x[b][ch][16k+t] -> fp16, chunk-swizzled.
// Plane path: fully-coalesced float4 plane load -> LDS -> strided reads
// (4-way bank conflict, cheap) -> packed fp16 16B chunk stores (each wave
// covers 16 rows x 64B fully). Wg path: 32x32 LDS transpose tiles.
// ---------------------------------------------------------------------------
__global__ __launch_bounds__(256) void kprep(const float* __restrict__ x,
                                             const float* __restrict__ wg) {
    const int bid = blockIdx.x, tid = threadIdx.x;
    if (bid < NB * NC) {
        __shared__ float sm[4096];
        const int b = bid >> 8, ch = bid & 255;
        const float4* src = reinterpret_cast<const float4*>(x) + ((size_t)(b * NC + ch) << 10);
        float4* s4 = reinterpret_cast<float4*>(sm);
#pragma unroll
        for (int v = 0; v < 4; ++v) s4[v * 256 + tid] = src[v * 256 + tid];
        __syncthreads();
        const int t = tid & 15, kb2 = tid >> 4;
        const int key = (ch >> 1) & 3;  // == (n>>1)&3 since (256t>>1)&3 == 0
        u16* row = g_xf + (((size_t)b << 12) + ch + (t << 8)) * NC;
#pragma unroll
        for (int h = 0; h < 2; ++h) {
            const int chunk = kb2 + h * 16;  // 8 k-values per 16B chunk
            uint32 pk[4];
#pragma unroll
            for (int p = 0; p < 4; ++p) {
                // k = 8*chunk + {2p, 2p+1}; plane elem 16k+t
                float f0 = sm[128 * chunk + 32 * p + t];
                float f1 = sm[128 * chunk + 32 * p + 16 + t];
                pk[p] = pkh(f0, f1);
            }
            const int phys = (chunk & ~3) | ((chunk & 3) ^ key);
            *reinterpret_cast<uint4*>(row + phys * 8) = make_uint4(pk[0], pk[1], pk[2], pk[3]);
        }
    } else {
        __shared__ float sm[32 * 33];
        const int b2 = bid - NB * NC;
        const int k0 = (b2 >> 3) * 32, c0 = (b2 & 7) * 32;
        {
            const int r = tid >> 3, cq = tid & 7;
            float4 v = *reinterpret_cast<const float4*>(wg + (k0 + r) * NC + c0 + cq * 4);
            float* d = sm + r * 33 + cq * 4;
            d[0] = v.x; d[1] = v.y; d[2] = v.z; d[3] = v.w;
        }
        __syncthreads();
        const int c = tid >> 3, kq = tid & 7;
        uint32 o0 = pkh(sm[(kq * 4 + 0) * 33 + c], sm[(kq * 4 + 1) * 33 + c]);
        uint32 o1 = pkh(sm[(kq * 4 + 2) * 33 + c], sm[(kq * 4 + 3) * 33 + c]);
        *reinterpret_cast<uint2*>(g_wf + (c0 + c) * NC + k0 + kq * 4) = make_uint2(o0, o1);
    }
}

// ---------------------------------------------------------------------------
// kfuse: hT-GEMM (fp16) + band-GEMM + bias, writes out[b][c][n] directly.
// Grid 512 = 8b x 2ct(128c) x 32nt(128n); 4 waves; wave = 32c x 160n-ext.
// B-tile (160 x 32k) double-buffered via global_load_lds(16B), shared by all
// waves; A (Wgt) preloaded to regs. Band: out[c,n] = sum_j g[c,j]*Bnd[j,n]
// via MFMA with 4 precomputed 0/1 Bnd vectors; KB in {f>>1, f>>1+1} only.
// ---------------------------------------------------------------------------
__global__ __launch_bounds__(256, 2) void kfuse(const float* __restrict__ bias,
                                                float* __restrict__ out) {
    __shared__ __attribute__((aligned(16))) char smem[43008];  // [2][10240] B-dbuf; then 4 x 10752 g-slab
    const int bid = blockIdx.x, tid = threadIdx.x;
    const int b = bid >> 6, ct = (bid >> 5) & 1, nt = bid & 31;
    const int w = tid >> 6, l = tid & 63;
    const int lr = l & 15, lk = l >> 4;
    const int wc0 = ct * 128 + w * 32;
    const int n0 = nt * 128, ne0 = n0 - 16;
    const int koff = (lk ^ ((lr >> 1) & 3)) << 4;  // de-swizzle byte offset

    // staging: 10 sub-tiles (16 rows x 64B) over 4 waves (w<2: 3, else 2)
    const int ni = (w < 2) ? 3 : 2;
    const char* gxc = (const char*)g_xf;
    size_t sgb[3]; int sld[3];
#pragma unroll
    for (int ii = 0; ii < 3; ++ii) {
        const int i = w + ii * 4;
        int n = ne0 + i * 16 + (l >> 2);
        n = n < 0 ? 0 : (n > NN - 1 ? NN - 1 : n);  // clamp; masked at g-slab
        sgb[ii] = (size_t)((b << 12) + n) * 512 + (l & 3) * 16;
        sld[ii] = i * 1024 + l * 16;
    }

    // preload all A fragments (Wgt fp16, L2-resident): 16 x 16B
    half8 af[8][2];
#pragma unroll
    for (int s = 0; s < 8; ++s)
#pragma unroll
        for (int cf = 0; cf < 2; ++cf)
            af[s][cf] = ldh8(g_wf + (wc0 + cf * 16 + lr) * NC + s * 32 + lk * 8);

    f32x4 acc[2][10] = {};

#define STAGE(CUR, S)                                                                         \
    _Pragma("unroll")                                                                         \
    for (int ii = 0; ii < 3; ++ii)                                                            \
        if (ii < ni)                                                                          \
            __builtin_amdgcn_global_load_lds(                                                 \
                (const __attribute__((address_space(1))) uint32*)(gxc + sgb[ii] + (S) * 64),  \
                (__attribute__((address_space(3))) uint32*)(smem + (CUR) * 10240 + sld[ii]),  \
                16, 0, 0);

    STAGE(0, 0)
    __syncthreads();
#pragma unroll
    for (int s = 0; s < 8; ++s) {
        const int cur = s & 1;
        if (s < 7) { STAGE(cur ^ 1, s + 1) }
        const char* bb = smem + cur * 10240;
#pragma unroll
        for (int f = 0; f < 10; ++f) {
            half8 bf = *reinterpret_cast<const half8*>(bb + (f * 16 + lr) * 64 + koff);
            acc[0][f] = __builtin_amdgcn_mfma_f32_16x16x32_f16(af[s][0], bf, acc[0][f], 0, 0, 0);
            acc[1][f] = __builtin_amdgcn_mfma_f32_16x16x32_f16(af[s][1], bf, acc[1][f], 0, 0, 0);
        }
        __syncthreads();  // next stage landed; everyone done reading cur
    }
#undef STAGE

    // g-slab: fp16 g = dinv_j * h (0 for OOB halo). 32 c-rows x 160 j, pitch 336B.
    char* gsl = smem + w * 10752;
    float dv[10];
#pragma unroll
    for (int f = 0; f < 10; ++f) {
        int n = ne0 + f * 16 + lr;
        dv[f] = (n >= 0 && n < NN) ? dinv_of(n) : 0.f;
    }
#pragma unroll
    for (int cf = 0; cf < 2; ++cf)
#pragma unroll
        for (int f = 0; f < 10; ++f)
#pragma unroll
            for (int v = 0; v < 4; ++v) {
                const int crow = cf * 16 + 4 * lk + v;
                _Float16 hv = (_Float16)(acc[cf][f][v] * dv[f]);
                *(u16*)(gsl + crow * 336 + (f * 16 + lr) * 2) = __builtin_bit_cast(u16, hv);
            }
    __syncthreads();  // also fences B-dbuf -> g-slab LDS reuse

    // band GEMM, hoisted operands.
    // d = j - n_local - 16 = KB*32 + 8lk - 16 - 16f - lr + jj reduces to
    // delta + jj with delta = 8lk - lr + {-16 (f even,t0), +16 (f even,t1),
    //                                     -32 (f odd,t0),    0 (f odd,t1)}
    half8 ga0v[5], ga1v[5];
#pragma unroll
    for (int KB = 0; KB < 5; ++KB) {
        ga0v[KB] = *reinterpret_cast<const half8*>(gsl + lr * 336 + KB * 64 + lk * 16);
        ga1v[KB] = *reinterpret_cast<const half8*>(gsl + (16 + lr) * 336 + KB * 64 + lk * 16);
    }
    const int dbase = 8 * lk - lr;
    half8 bnv[4];
#pragma unroll
    for (int pt = 0; pt < 4; ++pt) {
        const int off = (pt == 0) ? -16 : (pt == 1) ? 16 : (pt == 2) ? -32 : 0;
#pragma unroll
        for (int jj = 0; jj < 8; ++jj) {
            const int d = dbase + off + jj;
            bnv[pt][jj] = (d >= -9 && d <= 9) ? (_Float16)1.f : (_Float16)0.f;
        }
    }
    f32x4 acc2[2][8] = {};
#pragma unroll
    for (int f = 0; f < 8; ++f)
#pragma unroll
        for (int t = 0; t < 2; ++t) {
            const int KB = (f >> 1) + t;
            const half8 bn = bnv[(f & 1) * 2 + t];
            acc2[0][f] = __builtin_amdgcn_mfma_f32_16x16x32_f16(ga0v[KB], bn, acc2[0][f], 0, 0, 0);
            acc2[1][f] = __builtin_amdgcn_mfma_f32_16x16x32_f16(ga1v[KB], bn, acc2[1][f], 0, 0, 0);
        }

    float dnv[8];
#pragma unroll
    for (int f = 0; f < 8; ++f) dnv[f] = dinv_of(n0 + f * 16 + lr);
#pragma unroll
    for (int cf = 0; cf < 2; ++cf)
#pragma unroll
        for (int v = 0; v < 4; ++v) {
            const int c = wc0 + cf * 16 + 4 * lk + v;
            const float bc = bias[c];
            float* orow = out + (((size_t)(b * NC + c)) << 12) + n0;
#pragma unroll
            for (int f = 0; f < 8; ++f)
                orow[f * 16 + lr] = acc2[cf][f][v] * dnv[f] + bc;
        }
}

extern "C" void kernel_launch(void* const* d_in, const int* in_sizes, int n_in,
                              void* d_out, int out_size, void* d_ws, size_t ws_size,
                              hipStream_t stream) {
    const float* x  = (const float*)d_in[0];
    const float* wg = (const float*)d_in[1];
    const float* bs = (const float*)d_in[2];
    float* out = (float*)d_out;

    hipLaunchKernelGGL(kprep, dim3(NB * NC + 64), dim3(256), 0, stream, x, wg);
    hipLaunchKernelGGL(kfuse, dim3(512), dim3(256), 0, stream, bs, out);
}

// Round 11
// 102.372 us; speedup vs baseline: 1.6235x; 1.0028x over previous
//
#include <hip/hip_runtime.h>
#include <math.h>

typedef unsigned int uint32;
typedef unsigned short u16;
typedef _Float16 half8 __attribute__((ext_vector_type(8)));
typedef float f32x4 __attribute__((ext_vector_type(4)));

constexpr int NB = 8, NC = 256, NN = 4096;

// fp16 permuted x2[b][n][k]; 16B chunk m stored at phys = m ^ (n&7) so that a
// LINEAR identity copy into LDS [160][512] gives bank-conflict-free
// ds_read_b128 (slot = phys%8 spreads 8 lanes/bank-quad). Rewritten each launch.
__device__ __attribute__((aligned(16))) u16 g_xf[NB * NN * NC];  // 16.8 MB
__device__ __attribute__((aligned(16))) u16 g_wf[NC * NC];       // Wg^T [c][k] fp16

__device__ __forceinline__ float dinv_of(int n) {
    int lo = n - 9; lo = lo < 0 ? 0 : lo;
    int hi = n + 9; hi = hi > NN - 1 ? NN - 1 : hi;
    return 1.0f / sqrtf((float)(hi - lo + 1));  // deg incl. self-loop
}

__device__ __forceinline__ uint32 pkh(float a, float b) {
    _Float16 ha = (_Float16)a, hb = (_Float16)b;
    return (uint32)__builtin_bit_cast(u16, ha) | ((uint32)__builtin_bit_cast(u16, hb) << 16);
}

__device__ __forceinline__ half8 ldh8(const u16* p) {
    return __builtin_bit_cast(half8, *reinterpret_cast<const uint4*>(p));
}

// ---------------------------------------------------------------------------
// kprep: x2[b][n=ch+256t][k] = x[b][ch][16k+t] -> fp16, chunk m at m^(n&7).
// Coalesced float4 plane load -> LDS -> packed fp16 16B chunk stores
// (16 same-t threads cover 256B contiguous per row per h).
// ---------------------------------------------------------------------------
__global__ __launch_bounds__(256) void kprep(const float* __restrict__ x,
                                             const float* __restrict__ wg) {
    const int bid = blockIdx.x, tid = threadIdx.x;
    if (bid < NB * NC) {
        __shared__ float sm[4096];
        const int b = bid >> 8, ch = bid & 255;
        const float4* src = reinterpret_cast<const float4*>(x) + ((size_t)(b * NC + ch) << 10);
        float4* s4 = reinterpret_cast<float4*>(sm);
#pragma unroll
        for (int v = 0; v < 4; ++v) s4[v * 256 + tid] = src[v * 256 + tid];
        __syncthreads();
        const int t = tid & 15, kb2 = tid >> 4;
        const int key = ch & 7;  // == n&7 since n = ch + 256t
        u16* row = g_xf + (((size_t)b << 12) + ch + (t << 8)) * NC;
#pragma unroll
        for (int h = 0; h < 2; ++h) {
            const int chunk = kb2 + h * 16;  // 8 k-values per 16B chunk
            uint32 pk[4];
#pragma unroll
            for (int p = 0; p < 4; ++p) {
                float f0 = sm[128 * chunk + 32 * p + t];
                float f1 = sm[128 * chunk + 32 * p + 16 + t];
                pk[p] = pkh(f0, f1);
            }
            const int phys = chunk ^ key;  // key<8: bits 3..4 preserved, bijective
            *reinterpret_cast<uint4*>(row + phys * 8) = make_uint4(pk[0], pk[1], pk[2], pk[3]);
        }
    } else {
        __shared__ float sm2[32 * 33];
        const int b2 = bid - NB * NC;
        const int k0 = (b2 >> 3) * 32, c0 = (b2 & 7) * 32;
        {
            const int r = tid >> 3, cq = tid & 7;
            float4 v = *reinterpret_cast<const float4*>(wg + (k0 + r) * NC + c0 + cq * 4);
            float* d = sm2 + r * 33 + cq * 4;
            d[0] = v.x; d[1] = v.y; d[2] = v.z; d[3] = v.w;
        }
        __syncthreads();
        const int c = tid >> 3, kq = tid & 7;
        uint32 o0 = pkh(sm2[(kq * 4 + 0) * 33 + c], sm2[(kq * 4 + 1) * 33 + c]);
        uint32 o1 = pkh(sm2[(kq * 4 + 2) * 33 + c], sm2[(kq * 4 + 3) * 33 + c]);
        *reinterpret_cast<uint2*>(g_wf + (c0 + c) * NC + k0 + kq * 4) = make_uint2(o0, o1);
    }
}

// ---------------------------------------------------------------------------
// kfuse: hT-GEMM (fp16) + band-GEMM + bias -> out[b][c][n].
// Grid 512 = 8b x 2ct(128c) x 32nt(128n); 4 waves; wave = 32c x 160n-ext.
// Whole B-tile (160 x 512B = 80KB) staged in ONE shot (20 global_load_lds per
// wave, identity copy), ONE barrier, then all 160 MFMAs barrier-free.
// g-slab (4 x 32rows x 320B) overlays the B region after barrier 2; each wave
// reads only its own slab (program-order, no 3rd barrier). 2 blocks/CU.
// ---------------------------------------------------------------------------
__global__ __launch_bounds__(256, 2) void kfuse(const float* __restrict__ bias,
                                                float* __restrict__ out) {
    __shared__ __attribute__((aligned(16))) char smem[81920];
    const int bid = blockIdx.x, tid = threadIdx.x;
    const int b = bid >> 6, ct = (bid >> 5) & 1, nt = bid & 31;
    const int w = tid >> 6, l = tid & 63;
    const int lr = l & 15, lk = l >> 4;
    const int wc0 = ct * 128 + w * 32;
    const int n0 = nt * 128, ne0 = n0 - 16;

    // stage entire B-tile: instr gi covers rows 2gi..2gi+1 (1KB), lane l -> +l*16
    const char* gxc = (const char*)g_xf;
#pragma unroll
    for (int ii = 0; ii < 20; ++ii) {
        const int gi = w * 20 + ii;
        int n = ne0 + 2 * gi + (l >> 5);
        n = n < 0 ? 0 : (n > NN - 1 ? NN - 1 : n);  // clamp; dv-masked later
        __builtin_amdgcn_global_load_lds(
            (const __attribute__((address_space(1))) uint32*)(gxc + (size_t)((b << 12) + n) * 512 + (l & 31) * 16),
            (__attribute__((address_space(3))) uint32*)(smem + gi * 1024 + l * 16),
            16, 0, 0);
    }

    // preload all A fragments (Wgt fp16, L2/L3-resident): 16 x 16B
    half8 af[8][2];
#pragma unroll
    for (int s = 0; s < 8; ++s)
#pragma unroll
        for (int cf = 0; cf < 2; ++cf)
            af[s][cf] = ldh8(g_wf + (wc0 + cf * 16 + lr) * NC + s * 32 + lk * 8);

    __syncthreads();  // vmcnt(0) drain: whole B-tile resident

    f32x4 acc[2][10] = {};
#pragma unroll
    for (int s = 0; s < 8; ++s) {
        const int pbyte = (((4 * s + lk) ^ (lr & 7)) << 4);  // de-swizzled chunk
#pragma unroll
        for (int f = 0; f < 10; ++f) {
            half8 bf = *reinterpret_cast<const half8*>(smem + (f * 16 + lr) * 512 + pbyte);
            acc[0][f] = __builtin_amdgcn_mfma_f32_16x16x32_f16(af[s][0], bf, acc[0][f], 0, 0, 0);
            acc[1][f] = __builtin_amdgcn_mfma_f32_16x16x32_f16(af[s][1], bf, acc[1][f], 0, 0, 0);
        }
    }
    __syncthreads();  // all waves done reading B; safe to overlay g-slabs

    // g-slab: fp16 g = dinv_j * h (0 for OOB halo). 32 c-rows x 160 j, pitch 320B.
    char* gsl = smem + w * 10240;
    float dv[10];
#pragma unroll
    for (int f = 0; f < 10; ++f) {
        int n = ne0 + f * 16 + lr;
        dv[f] = (n >= 0 && n < NN) ? dinv_of(n) : 0.f;
    }
#pragma unroll
    for (int cf = 0; cf < 2; ++cf)
#pragma unroll
        for (int f = 0; f < 10; ++f)
#pragma unroll
            for (int v = 0; v < 4; ++v) {
                const int crow = cf * 16 + 4 * lk + v;
                _Float16 hv = (_Float16)(acc[cf][f][v] * dv[f]);
                *(u16*)(gsl + crow * 320 + (f * 16 + lr) * 2) = __builtin_bit_cast(u16, hv);
            }
    // wave reads only its own slab below: program-order lgkmcnt suffices.

    // band GEMM, hoisted operands. pitch 320 = 20x16B: quad slot
    // (20lr+4KB+lk)%8 = 4(lr&1)+... -> 8 lanes/quad, conflict-free.
    half8 ga0v[5], ga1v[5];
#pragma unroll
    for (int KB = 0; KB < 5; ++KB) {
        ga0v[KB] = *reinterpret_cast<const half8*>(gsl + lr * 320 + KB * 64 + lk * 16);
        ga1v[KB] = *reinterpret_cast<const half8*>(gsl + (16 + lr) * 320 + KB * 64 + lk * 16);
    }
    // d = j - n_local - 16 reduces to (8lk - lr + off) + jj with
    // off = {-16 (f even,t0), +16 (f even,t1), -32 (f odd,t0), 0 (f odd,t1)}
    const int dbase = 8 * lk - lr;
    half8 bnv[4];
#pragma unroll
    for (int pt = 0; pt < 4; ++pt) {
        const int off = (pt == 0) ? -16 : (pt == 1) ? 16 : (pt == 2) ? -32 : 0;
#pragma unroll
        for (int jj = 0; jj < 8; ++jj) {
            const int d = dbase + off + jj;
            bnv[pt][jj] = (d >= -9 && d <= 9) ? (_Float16)1.f : (_Float16)0.f;
        }
    }
    f32x4 acc2[2][8] = {};
#pragma unroll
    for (int f = 0; f < 8; ++f)
#pragma unroll
        for (int t = 0; t < 2; ++t) {
            const int KB = (f >> 1) + t;
            const half8 bn = bnv[(f & 1) * 2 + t];
            acc2[0][f] = __builtin_amdgcn_mfma_f32_16x16x32_f16(ga0v[KB], bn, acc2[0][f], 0, 0, 0);
            acc2[1][f] = __builtin_amdgcn_mfma_f32_16x16x32_f16(ga1v[KB], bn, acc2[1][f], 0, 0, 0);
        }

    float dnv[8];
#pragma unroll
    for (int f = 0; f < 8; ++f) dnv[f] = dinv_of(n0 + f * 16 + lr);
#pragma unroll
    for (int cf = 0; cf < 2; ++cf)
#pragma unroll
        for (int v = 0; v < 4; ++v) {
            const int c = wc0 + cf * 16 + 4 * lk + v;
            const float bc = bias[c];
            float* orow = out + (((size_t)(b * NC + c)) << 12) + n0;
#pragma unroll
            for (int f = 0; f < 8; ++f)
                orow[f * 16 + lr] = acc2[cf][f][v] * dnv[f] + bc;
        }
}

extern "C" void kernel_launch(void* const* d_in, const int* in_sizes, int n_in,
                              void* d_out, int out_size, void* d_ws, size_t ws_size,
                              hipStream_t stream) {
    const float* x  = (const float*)d_in[0];
    const float* wg = (const float*)d_in[1];
    const float* bs = (const float*)d_in[2];
    float* out = (float*)d_out;

    hipLaunchKernelGGL(kprep, dim3(NB * NC + 64), dim3(256), 0, stream, x, wg);
    hipLaunchKernelGGL(kfuse, dim3(512), dim3(256), 0, stream, bs, out);
}